// Round 7
// baseline (1807.746 us; speedup 1.0000x reference)
//
#include <hip/hip_runtime.h>
#include <cmath>

#define NN 100000
#define NE 3200000
#define C 128
#define NLAYERS 8
#define PSTRIDE 96  // padded CSR row stride; Poisson(32) max-degree +11 sigma

// edge binning (no global atomics; scatter was mem-side-atomic-throughput-bound)
#define NBUCK 391  // ceil(NN/256) buckets of 256 dst nodes
#define EPB 4096   // edges per binpass block
#define NBLK 782   // ceil(NE/EPB)
#define SEGCAP 48  // per-(block,bucket) capacity: lambda=10.5, +11.6 sigma

typedef unsigned int u32;
typedef unsigned short u16;
typedef __attribute__((ext_vector_type(8))) short s16x8;
typedef __attribute__((ext_vector_type(4))) float f32x4;
typedef __attribute__((ext_vector_type(4))) int i32x4;

__device__ __forceinline__ float bf2f(u16 u) { return __uint_as_float(((u32)u) << 16); }
__device__ __forceinline__ u16 f2bf(float f) {
    u32 x = __float_as_uint(f);
    return (u16)((x + 0x7fffu + ((x >> 16) & 1u)) >> 16);  // RNE
}

// ---------------- setup: bucketed CSR build (no global atomics) ----------------

__global__ __launch_bounds__(256) void binpass(
    const int* __restrict__ row, const int* __restrict__ col,
    u32* __restrict__ barr, u32* __restrict__ bcnt) {
    __shared__ u32 hist[NBUCK];
    int tid = threadIdx.x, blk = blockIdx.x;
    for (int i = tid; i < NBUCK; i += 256) hist[i] = 0;
    __syncthreads();
    int e0 = blk * EPB;
    int ee = min(e0 + EPB, NE);
    u32 segbase = (u32)blk * NBUCK * SEGCAP;
    for (int e = e0 + tid; e < ee; e += 256) {
        int d = __builtin_nontemporal_load(col + e);
        int s = __builtin_nontemporal_load(row + e);
        int b = d >> 8;
        u32 r = atomicAdd(&hist[b], 1u);
        if (r < SEGCAP)  // statistically impossible overflow guard
            __builtin_nontemporal_store((u32)s | ((u32)(d & 255) << 17),
                                        barr + segbase + (u32)b * SEGCAP + r);
    }
    __syncthreads();
    for (int i = tid; i < NBUCK; i += 256)
        bcnt[(size_t)i * NBLK + blk] = min(hist[i], (u32)SEGCAP);  // [bucket][blk]
}

// 1024 threads: 16 waves -> 49 serial segment-iterations; dinv fused.
__global__ __launch_bounds__(1024) void fillpass(
    const u32* __restrict__ barr, const u32* __restrict__ bcnt,
    int* __restrict__ csr, int* __restrict__ cnt, float* __restrict__ dinv) {
    __shared__ u32 counts[NBLK];
    __shared__ u32 lcnt[256];
    int tid = threadIdx.x, b = blockIdx.x;
    for (int i = tid; i < NBLK; i += 1024)
        counts[i] = __builtin_nontemporal_load(bcnt + (size_t)b * NBLK + i);
    if (tid < 256) lcnt[tid] = 0;
    __syncthreads();
    int wave = tid >> 6, lane = tid & 63;
    int nb0 = b << 8;
    int seg = wave;  // wave < 16 < NBLK always
    u32 c = counts[seg];
    u32 val = (lane < (int)c)
                  ? __builtin_nontemporal_load(barr + ((u32)seg * NBUCK + b) * SEGCAP + lane)
                  : 0u;
    while (true) {
        int segn = seg + 16;
        u32 cn = 0, valn = 0;
        if (segn < NBLK) {
            cn = counts[segn];
            if (lane < (int)cn)
                valn = __builtin_nontemporal_load(barr + ((u32)segn * NBUCK + b) * SEGCAP + lane);
        }
        if (lane < (int)c) {
            int local = (int)(val >> 17);
            u32 slot = atomicAdd(&lcnt[local], 1u);
            __builtin_nontemporal_store((int)(val & 0x1FFFFu),
                                        csr + (size_t)(nb0 + local) * PSTRIDE + slot);
        }
        if (segn >= NBLK) break;
        seg = segn; c = cn; val = valn;
    }
    __syncthreads();
    if (tid < 256 && nb0 + tid < NN) {
        u32 d = lcnt[tid];
        cnt[nb0 + tid] = (int)d;
        dinv[nb0 + tid] = rsqrtf((float)(d + 1));  // +1 self loop
    }
}

// Weights -> bf16 hi/lo in B-fragment layout Wb[mat][n*128+k]; layer mats
// FOLDED: W'_l = beta_l*W_l + (1-beta_l)*I  (raw = z@W' kills z epilogue reads).
__global__ void prep_w(const float* __restrict__ Wp, const float* __restrict__ cw,
                       u16* __restrict__ Wbh, u16* __restrict__ Wbl) {
    int tid = blockIdx.x * blockDim.x + threadIdx.x;
    if (tid >= 9 * C * C) return;
    int mat = tid >> 14;
    int r = tid & 16383;
    int n = r >> 7, k = r & 127;
    float v;
    if (mat == 0) {
        v = Wp[k * C + n];
    } else {
        float beta = logf(0.5f / (float)mat + 1.0f);  // beta_{mat-1}
        v = beta * cw[(size_t)(mat - 1) * C * C + k * C + n] +
            ((k == n) ? (1.0f - beta) : 0.0f);
    }
    u16 hi = f2bf(v);
    float lo = v - bf2f(hi);
    Wbh[tid] = hi;
    Wbl[tid] = f2bf(lo);
}

// ---------------- GEMM proj (MFMA 16x16x32 bf16, hi/lo split) --------------

__device__ __forceinline__ void build_a(f32x4 pa, f32x4 pb, s16x8& hi, s16x8& lo) {
#pragma unroll
    for (int j = 0; j < 4; ++j) {
        float v = pa[j];
        u16 h = f2bf(v);
        hi[j] = (short)h;
        lo[j] = (short)f2bf(v - bf2f(h));
    }
#pragma unroll
    for (int j = 0; j < 4; ++j) {
        float v = pb[j];
        u16 h = f2bf(v);
        hi[4 + j] = (short)h;
        lo[4 + j] = (short)f2bf(v - bf2f(h));
    }
}

__global__ __launch_bounds__(256) void gemm_proj(
    const float* __restrict__ X, const u16* __restrict__ Wbh, const u16* __restrict__ Wbl,
    const float* __restrict__ bias, const float* __restrict__ dinv,
    u16* __restrict__ x0bf, float* __restrict__ h32, u16* __restrict__ gbf) {
    int tid = threadIdx.x;
    int wave = tid >> 6, lane = tid & 63;
    int quad = lane >> 4, l16 = lane & 15;
    int rowbase = blockIdx.x * 64 + wave * 16;
    int arow = rowbase + l16;
    if (arow >= NN) arow = NN - 1;
    const float* aptr = X + (size_t)arow * C + quad * 8;
    s16x8 ahi[4], alo[4];
#pragma unroll
    for (int c2 = 0; c2 < 4; ++c2) {
        f32x4 pa = __builtin_nontemporal_load((const f32x4*)(aptr + c2 * 32));
        f32x4 pb = __builtin_nontemporal_load((const f32x4*)(aptr + c2 * 32 + 4));
        build_a(pa, pb, ahi[c2], alo[c2]);
    }
    f32x4 acc[8];
#pragma unroll
    for (int t = 0; t < 8; ++t) acc[t] = f32x4{0.f, 0.f, 0.f, 0.f};
#pragma unroll
    for (int c2 = 0; c2 < 4; ++c2) {
#pragma unroll
        for (int t = 0; t < 8; ++t) {
            int widx = (t * 16 + l16) * C + c2 * 32 + quad * 8;
            s16x8 bh = *(const s16x8*)(Wbh + widx);
            s16x8 bl = *(const s16x8*)(Wbl + widx);
            acc[t] = __builtin_amdgcn_mfma_f32_16x16x32_bf16(ahi[c2], bh, acc[t], 0, 0, 0);
            acc[t] = __builtin_amdgcn_mfma_f32_16x16x32_bf16(alo[c2], bh, acc[t], 0, 0, 0);
            acc[t] = __builtin_amdgcn_mfma_f32_16x16x32_bf16(ahi[c2], bl, acc[t], 0, 0, 0);
        }
    }
    float dv[4];
#pragma unroll
    for (int r = 0; r < 4; ++r) {
        int m = rowbase + quad * 4 + r;
        dv[r] = (m < NN) ? dinv[m] : 0.f;
    }
#pragma unroll
    for (int t = 0; t < 8; ++t) {
        int n = t * 16 + l16;
        float bv = bias[n];
#pragma unroll
        for (int r = 0; r < 4; ++r) {
            int m = rowbase + quad * 4 + r;
            if (m < NN) {
                float v = acc[t][r] + bv;
                size_t idx = (size_t)m * C + n;
                __builtin_nontemporal_store(v, h32 + idx);
                __builtin_nontemporal_store(f2bf(v), x0bf + idx);
                __builtin_nontemporal_store(f2bf(dv[r] * v), gbf + idx);
            }
        }
    }
}

// ------- fused layer v2 + NT streams: agg loop -> z in 8KB LDS -> M=16 MFMA --
// One-touch streams (csr, x0, h32, out32, gout) are non-temporal so they can't
// evict the 25.6 MB gather table from the per-XCD L2s. Gather rows, self-loop
// row, weights, cnt/dinv stay temporal (the data L2 should keep).

__global__ __launch_bounds__(256) void agg_gemm2(
    const u16* __restrict__ gin, const u16* __restrict__ x0bf,
    const int* __restrict__ cnt, const int* __restrict__ csr,
    const float* __restrict__ dinv,
    const u16* __restrict__ Wbh, const u16* __restrict__ Wbl,
    const float* __restrict__ h32, float* __restrict__ out32,
    u16* __restrict__ gout, int relu) {
    __shared__ u16 zh_lds[16 * C];  // 4 KB
    __shared__ u16 zl_lds[16 * C];  // 4 KB
    int tid = threadIdx.x;
    int wave = tid >> 6, lane = tid & 63;
    int grp = lane >> 4, l16 = lane & 15;
    int rowbase = blockIdx.x * 16;  // grid is exact: 6250*16 = NN
    const char* gb = (const char*)gin + l16 * 16;

#define ACC8(vv)                                                          \
    {                                                                     \
        u32 x_;                                                           \
        x_ = (u32)(vv).x; a0 += bf2f((u16)x_); a1 += bf2f((u16)(x_ >> 16)); \
        x_ = (u32)(vv).y; a2 += bf2f((u16)x_); a3 += bf2f((u16)(x_ >> 16)); \
        x_ = (u32)(vv).z; a4 += bf2f((u16)x_); a5 += bf2f((u16)(x_ >> 16)); \
        x_ = (u32)(vv).w; a6 += bf2f((u16)x_); a7 += bf2f((u16)(x_ >> 16)); \
    }

    // ---------------- agg phase: 4 nodes per wave ----------------
    for (int it = 0; it < 4; ++it) {
        int lrow = wave * 4 + it;
        int node = rowbase + lrow;
        int deg = __builtin_amdgcn_readfirstlane(cnt[node]);
        const int* cp = csr + (size_t)node * PSTRIDE;
        float a0 = 0.f, a1 = 0.f, a2 = 0.f, a3 = 0.f, a4 = 0.f, a5 = 0.f, a6 = 0.f, a7 = 0.f;
        int nch = (deg + 15) >> 4;  // chunks of 16 neighbors
        if (nch > 0) {
            int dm1 = deg - 1;
            int s0 = __builtin_nontemporal_load(cp + min(grp, dm1));
            int s1 = __builtin_nontemporal_load(cp + min(grp + 4, dm1));
            int s2 = __builtin_nontemporal_load(cp + min(grp + 8, dm1));
            int s3 = __builtin_nontemporal_load(cp + min(grp + 12, dm1));
            for (int c = 0; c < nch; ++c) {
                int4 v0 = *(const int4*)(gb + (size_t)(u32)s0 * 256);
                int4 v1 = *(const int4*)(gb + (size_t)(u32)s1 * 256);
                int4 v2 = *(const int4*)(gb + (size_t)(u32)s2 * 256);
                int4 v3 = *(const int4*)(gb + (size_t)(u32)s3 * 256);
                bool more = (c + 1) < nch;
                if (more) {
                    int nb = (c + 1) << 4;
                    s0 = __builtin_nontemporal_load(cp + min(nb + grp, dm1));
                    s1 = __builtin_nontemporal_load(cp + min(nb + grp + 4, dm1));
                    s2 = __builtin_nontemporal_load(cp + min(nb + grp + 8, dm1));
                    s3 = __builtin_nontemporal_load(cp + min(nb + grp + 12, dm1));
                }
                int cb = c << 4;
                if (cb + 16 <= deg) {  // wave-uniform: full chunk
                    ACC8(v0); ACC8(v1); ACC8(v2); ACC8(v3);
                } else {  // tail: zero-mask invalid rows (adding +0.0 is safe)
                    int m0 = (cb + grp < deg) ? -1 : 0;
                    int m1 = (cb + grp + 4 < deg) ? -1 : 0;
                    int m2 = (cb + grp + 8 < deg) ? -1 : 0;
                    int m3 = (cb + grp + 12 < deg) ? -1 : 0;
                    v0.x &= m0; v0.y &= m0; v0.z &= m0; v0.w &= m0;
                    v1.x &= m1; v1.y &= m1; v1.z &= m1; v1.w &= m1;
                    v2.x &= m2; v2.y &= m2; v2.z &= m2; v2.w &= m2;
                    v3.x &= m3; v3.y &= m3; v3.z &= m3; v3.w &= m3;
                    ACC8(v0); ACC8(v1); ACC8(v2); ACC8(v3);
                }
            }
        }
        a0 += __shfl_xor(a0, 16); a0 += __shfl_xor(a0, 32);
        a1 += __shfl_xor(a1, 16); a1 += __shfl_xor(a1, 32);
        a2 += __shfl_xor(a2, 16); a2 += __shfl_xor(a2, 32);
        a3 += __shfl_xor(a3, 16); a3 += __shfl_xor(a3, 32);
        a4 += __shfl_xor(a4, 16); a4 += __shfl_xor(a4, 32);
        a5 += __shfl_xor(a5, 16); a5 += __shfl_xor(a5, 32);
        a6 += __shfl_xor(a6, 16); a6 += __shfl_xor(a6, 32);
        a7 += __shfl_xor(a7, 16); a7 += __shfl_xor(a7, 32);
        // self-loop term (added once per lane, post-reduce; table row = temporal)
        int4 sv = *(const int4*)((const char*)gin + (size_t)node * 256 + l16 * 16);
        ACC8(sv);
        float dv = dinv[node];
        i32x4 xv = __builtin_nontemporal_load(
            (const i32x4*)((const char*)x0bf + (size_t)node * 256 + l16 * 16));
        float av[8] = {a0, a1, a2, a3, a4, a5, a6, a7};
        u32 xs[4] = {(u32)xv.x, (u32)xv.y, (u32)xv.z, (u32)xv.w};
        float xf[8];
        xf[0] = bf2f((u16)xs[0]); xf[1] = bf2f((u16)(xs[0] >> 16));
        xf[2] = bf2f((u16)xs[1]); xf[3] = bf2f((u16)(xs[1] >> 16));
        xf[4] = bf2f((u16)xs[2]); xf[5] = bf2f((u16)(xs[2] >> 16));
        xf[6] = bf2f((u16)xs[3]); xf[7] = bf2f((u16)(xs[3] >> 16));
        u32 hp[4], lp[4];
#pragma unroll
        for (int k = 0; k < 4; ++k) {
            float z0 = 0.9f * dv * av[2 * k] + 0.1f * xf[2 * k];
            float z1 = 0.9f * dv * av[2 * k + 1] + 0.1f * xf[2 * k + 1];
            u16 h0 = f2bf(z0), h1 = f2bf(z1);
            u16 l0 = f2bf(z0 - bf2f(h0)), l1 = f2bf(z1 - bf2f(h1));
            hp[k] = (u32)h0 | ((u32)h1 << 16);
            lp[k] = (u32)l0 | ((u32)l1 << 16);
        }
        int bo = (l16 * 16) ^ ((lrow & 7) << 4);  // swizzled byte off in row
        if (grp == 0) {
            int4 o; o.x = (int)hp[0]; o.y = (int)hp[1]; o.z = (int)hp[2]; o.w = (int)hp[3];
            *(int4*)((char*)zh_lds + lrow * 256 + bo) = o;
        } else if (grp == 1) {
            int4 o; o.x = (int)lp[0]; o.y = (int)lp[1]; o.z = (int)lp[2]; o.w = (int)lp[3];
            *(int4*)((char*)zl_lds + lrow * 256 + bo) = o;
        }
    }
#undef ACC8
    __syncthreads();

    // ---------------- GEMM phase: M=16, wave owns n-tiles t=wave*2,wave*2+1 --
    s16x8 ahi[4], alo[4];
#pragma unroll
    for (int c2 = 0; c2 < 4; ++c2) {
        int bo = (c2 * 64 + grp * 16) ^ ((l16 & 7) << 4);
        ahi[c2] = *(const s16x8*)((const char*)zh_lds + l16 * 256 + bo);
        alo[c2] = *(const s16x8*)((const char*)zl_lds + l16 * 256 + bo);
    }
    f32x4 acc[2];
    acc[0] = f32x4{0.f, 0.f, 0.f, 0.f};
    acc[1] = f32x4{0.f, 0.f, 0.f, 0.f};
#pragma unroll
    for (int c2 = 0; c2 < 4; ++c2) {
#pragma unroll
        for (int tt = 0; tt < 2; ++tt) {
            int t = wave * 2 + tt;
            int widx = (t * 16 + l16) * C + c2 * 32 + grp * 8;
            s16x8 bh = *(const s16x8*)(Wbh + widx);
            s16x8 bl = *(const s16x8*)(Wbl + widx);
            acc[tt] = __builtin_amdgcn_mfma_f32_16x16x32_bf16(ahi[c2], bh, acc[tt], 0, 0, 0);
            acc[tt] = __builtin_amdgcn_mfma_f32_16x16x32_bf16(alo[c2], bh, acc[tt], 0, 0, 0);
            acc[tt] = __builtin_amdgcn_mfma_f32_16x16x32_bf16(ahi[c2], bl, acc[tt], 0, 0, 0);
        }
    }
    float dvr[4];
#pragma unroll
    for (int r = 0; r < 4; ++r) dvr[r] = dinv[rowbase + grp * 4 + r];
#pragma unroll
    for (int tt = 0; tt < 2; ++tt) {
        int n = (wave * 2 + tt) * 16 + l16;
#pragma unroll
        for (int r = 0; r < 4; ++r) {
            int m = rowbase + grp * 4 + r;
            size_t idx = (size_t)m * C + n;
            float hn = acc[tt][r] + __builtin_nontemporal_load(h32 + idx);
            if (relu) hn = fmaxf(hn, 0.f);
            __builtin_nontemporal_store(hn, out32 + idx);
            __builtin_nontemporal_store(f2bf(dvr[r] * hn), gout + idx);
        }
    }
}

// ---------------- host ----------------

extern "C" void kernel_launch(void* const* d_in, const int* in_sizes, int n_in,
                              void* d_out, int out_size, void* d_ws, size_t ws_size,
                              hipStream_t stream) {
    const float* x = (const float*)d_in[0];
    const int* ei = (const int*)d_in[1];
    const float* Wp = (const float*)d_in[2];
    const float* bp = (const float*)d_in[3];
    const float* cw = (const float*)d_in[4];
    const int* row = ei;
    const int* col = ei + NE;

    char* ws = (char*)d_ws;
    size_t o = 0;
    auto alloc = [&](size_t bytes) {
        void* p = ws + o;
        o += (bytes + 255) & ~(size_t)255;
        return p;
    };
    int* cnt = (int*)alloc(NN * 4);
    float* dinv = (float*)alloc(NN * 4);
    int* csr = (int*)alloc((size_t)NN * PSTRIDE * 4);
    u16* x0bf = (u16*)alloc((size_t)NN * C * 2);
    u16* gbufA = (u16*)alloc((size_t)NN * C * 2);
    u16* gbufB = (u16*)alloc((size_t)NN * C * 2);
    float* h32 = (float*)alloc((size_t)NN * C * 4);
    u16* Wbh = (u16*)alloc((size_t)9 * C * C * 2);
    u16* Wbl = (u16*)alloc((size_t)9 * C * C * 2);

    // binning scratch ALIASES x0bf..h32 (76.8+ MB): barr 58.7 MB + bcnt 1.2 MB,
    // fully consumed by fillpass before gemm_proj first writes x0bf/gbufA/h32.
    char* scratch = (char*)x0bf;
    u32* barr = (u32*)scratch;
    u32* bcnt = (u32*)(scratch + (size_t)NBLK * NBUCK * SEGCAP * 4);

    binpass<<<NBLK, 256, 0, stream>>>(row, col, barr, bcnt);
    fillpass<<<NBUCK, 1024, 0, stream>>>(barr, bcnt, csr, cnt, dinv);
    prep_w<<<(9 * C * C + 255) / 256, 256, 0, stream>>>(Wp, cw, Wbh, Wbl);
    gemm_proj<<<(NN + 63) / 64, 256, 0, stream>>>(x, Wbh, Wbl, bp, dinv, x0bf, h32, gbufA);

    u16* ga = gbufA;   // gather-table in
    u16* gb2 = gbufB;  // gather-table out (ping-pong: same-launch R/W otherwise)
    for (int l = 0; l < NLAYERS; ++l) {
        float* out32 = (l == NLAYERS - 1) ? (float*)d_out : h32;
        agg_gemm2<<<NN / 16, 256, 0, stream>>>(
            ga, x0bf, cnt, csr, dinv,
            Wbh + (size_t)(l + 1) * C * C, Wbl + (size_t)(l + 1) * C * C,
            h32, out32, gb2, (l < NLAYERS - 1) ? 1 : 0);
        u16* tmp = ga; ga = gb2; gb2 = tmp;
    }
}

// Round 8
// 1444.166 us; speedup vs baseline: 1.2518x; 1.2518x over previous
//
#include <hip/hip_runtime.h>
#include <cmath>

#define NN 100000
#define NE 3200000
#define C 128
#define NLAYERS 8
#define PSTRIDE 96  // padded CSR row stride; Poisson(32) max-degree +11 sigma

// edge binning (no global atomics; scatter was mem-side-atomic-throughput-bound)
#define NBUCK 391  // ceil(NN/256) buckets of 256 dst nodes
#define EPB 4096   // edges per binpass block
#define NBLK 782   // ceil(NE/EPB)
#define SEGCAP 48  // per-(block,bucket) capacity: lambda=10.5, +11.6 sigma

typedef unsigned int u32;
typedef unsigned short u16;
typedef __attribute__((ext_vector_type(8))) short s16x8;
typedef __attribute__((ext_vector_type(4))) float f32x4;

__device__ __forceinline__ float bf2f(u16 u) { return __uint_as_float(((u32)u) << 16); }
__device__ __forceinline__ u16 f2bf(float f) {
    u32 x = __float_as_uint(f);
    return (u16)((x + 0x7fffu + ((x >> 16) & 1u)) >> 16);  // RNE
}

// ---------------- setup: bucketed CSR build (no global atomics) ----------------

__global__ __launch_bounds__(256) void binpass(
    const int* __restrict__ row, const int* __restrict__ col,
    u32* __restrict__ barr, u32* __restrict__ bcnt) {
    __shared__ u32 hist[NBUCK];
    int tid = threadIdx.x, blk = blockIdx.x;
    for (int i = tid; i < NBUCK; i += 256) hist[i] = 0;
    __syncthreads();
    int e0 = blk * EPB;
    int ee = min(e0 + EPB, NE);
    u32 segbase = (u32)blk * NBUCK * SEGCAP;
    for (int e = e0 + tid; e < ee; e += 256) {
        int d = col[e];
        int s = row[e];
        int b = d >> 8;
        u32 r = atomicAdd(&hist[b], 1u);
        if (r < SEGCAP)  // statistically impossible overflow guard
            barr[segbase + (u32)b * SEGCAP + r] = (u32)s | ((u32)(d & 255) << 17);
    }
    __syncthreads();
    for (int i = tid; i < NBUCK; i += 256)
        bcnt[(size_t)i * NBLK + blk] = min(hist[i], (u32)SEGCAP);  // [bucket][blk]
}

// 1024 threads: 16 waves -> 49 serial segment-iterations; dinv fused.
__global__ __launch_bounds__(1024) void fillpass(
    const u32* __restrict__ barr, const u32* __restrict__ bcnt,
    int* __restrict__ csr, int* __restrict__ cnt, float* __restrict__ dinv) {
    __shared__ u32 counts[NBLK];
    __shared__ u32 lcnt[256];
    int tid = threadIdx.x, b = blockIdx.x;
    for (int i = tid; i < NBLK; i += 1024) counts[i] = bcnt[(size_t)b * NBLK + i];
    if (tid < 256) lcnt[tid] = 0;
    __syncthreads();
    int wave = tid >> 6, lane = tid & 63;
    int nb0 = b << 8;
    int seg = wave;  // wave < 16 < NBLK always
    u32 c = counts[seg];
    u32 val = (lane < (int)c) ? barr[((u32)seg * NBUCK + b) * SEGCAP + lane] : 0u;
    while (true) {
        int segn = seg + 16;
        u32 cn = 0, valn = 0;
        if (segn < NBLK) {
            cn = counts[segn];
            if (lane < (int)cn) valn = barr[((u32)segn * NBUCK + b) * SEGCAP + lane];
        }
        if (lane < (int)c) {
            int local = (int)(val >> 17);
            u32 slot = atomicAdd(&lcnt[local], 1u);
            csr[(size_t)(nb0 + local) * PSTRIDE + slot] = (int)(val & 0x1FFFFu);
        }
        if (segn >= NBLK) break;
        seg = segn; c = cn; val = valn;
    }
    __syncthreads();
    if (tid < 256 && nb0 + tid < NN) {
        u32 d = lcnt[tid];
        cnt[nb0 + tid] = (int)d;
        dinv[nb0 + tid] = rsqrtf((float)(d + 1));  // +1 self loop
    }
}

// Weights -> bf16 hi/lo in B-fragment layout Wb[mat][n*128+k]; layer mats
// FOLDED: W'_l = beta_l*W_l + (1-beta_l)*I  (raw = z@W' kills z epilogue reads).
__global__ void prep_w(const float* __restrict__ Wp, const float* __restrict__ cw,
                       u16* __restrict__ Wbh, u16* __restrict__ Wbl) {
    int tid = blockIdx.x * blockDim.x + threadIdx.x;
    if (tid >= 9 * C * C) return;
    int mat = tid >> 14;
    int r = tid & 16383;
    int n = r >> 7, k = r & 127;
    float v;
    if (mat == 0) {
        v = Wp[k * C + n];
    } else {
        float beta = logf(0.5f / (float)mat + 1.0f);  // beta_{mat-1}
        v = beta * cw[(size_t)(mat - 1) * C * C + k * C + n] +
            ((k == n) ? (1.0f - beta) : 0.0f);
    }
    u16 hi = f2bf(v);
    float lo = v - bf2f(hi);
    Wbh[tid] = hi;
    Wbl[tid] = f2bf(lo);
}

// ---------------- GEMM proj (MFMA 16x16x32 bf16, hi/lo split) --------------

__device__ __forceinline__ void build_a(const float* __restrict__ p, s16x8& hi, s16x8& lo) {
#pragma unroll
    for (int j = 0; j < 8; ++j) {
        float v = p[j];
        u16 h = f2bf(v);
        hi[j] = (short)h;
        lo[j] = (short)f2bf(v - bf2f(h));
    }
}

__global__ __launch_bounds__(256) void gemm_proj(
    const float* __restrict__ X, const u16* __restrict__ Wbh, const u16* __restrict__ Wbl,
    const float* __restrict__ bias, const float* __restrict__ dinv,
    u16* __restrict__ x0bf, float* __restrict__ h32, u16* __restrict__ gbf) {
    int tid = threadIdx.x;
    int wave = tid >> 6, lane = tid & 63;
    int quad = lane >> 4, l16 = lane & 15;
    int rowbase = blockIdx.x * 64 + wave * 16;
    int arow = rowbase + l16;
    if (arow >= NN) arow = NN - 1;
    const float* aptr = X + (size_t)arow * C + quad * 8;
    s16x8 ahi[4], alo[4];
#pragma unroll
    for (int c2 = 0; c2 < 4; ++c2) build_a(aptr + c2 * 32, ahi[c2], alo[c2]);
    f32x4 acc[8];
#pragma unroll
    for (int t = 0; t < 8; ++t) acc[t] = f32x4{0.f, 0.f, 0.f, 0.f};
#pragma unroll
    for (int c2 = 0; c2 < 4; ++c2) {
#pragma unroll
        for (int t = 0; t < 8; ++t) {
            int widx = (t * 16 + l16) * C + c2 * 32 + quad * 8;
            s16x8 bh = *(const s16x8*)(Wbh + widx);
            s16x8 bl = *(const s16x8*)(Wbl + widx);
            acc[t] = __builtin_amdgcn_mfma_f32_16x16x32_bf16(ahi[c2], bh, acc[t], 0, 0, 0);
            acc[t] = __builtin_amdgcn_mfma_f32_16x16x32_bf16(alo[c2], bh, acc[t], 0, 0, 0);
            acc[t] = __builtin_amdgcn_mfma_f32_16x16x32_bf16(ahi[c2], bl, acc[t], 0, 0, 0);
        }
    }
    float dv[4];
#pragma unroll
    for (int r = 0; r < 4; ++r) {
        int m = rowbase + quad * 4 + r;
        dv[r] = (m < NN) ? dinv[m] : 0.f;
    }
#pragma unroll
    for (int t = 0; t < 8; ++t) {
        int n = t * 16 + l16;
        float bv = bias[n];
#pragma unroll
        for (int r = 0; r < 4; ++r) {
            int m = rowbase + quad * 4 + r;
            if (m < NN) {
                float v = acc[t][r] + bv;
                size_t idx = (size_t)m * C + n;
                h32[idx] = v;
                x0bf[idx] = f2bf(v);
                gbf[idx] = f2bf(dv[r] * v);
            }
        }
    }
}

// ------- fused layer v3: round-6 structure + issue-early h32/dinv prefetch --
// Block = 256 thr / 4 waves / 16 nodes. Epilogue inputs (8 h32 + 4 dinv per
// thread) are loaded at kernel entry so their latency hides under the agg
// phase (T14 issue-early/use-late). Everything else identical to round 6.

__global__ __launch_bounds__(256) void agg_gemm2(
    const u16* __restrict__ gin, const u16* __restrict__ x0bf,
    const int* __restrict__ cnt, const int* __restrict__ csr,
    const float* __restrict__ dinv,
    const u16* __restrict__ Wbh, const u16* __restrict__ Wbl,
    const float* __restrict__ h32, float* __restrict__ out32,
    u16* __restrict__ gout, int relu) {
    __shared__ u16 zh_lds[16 * C];  // 4 KB
    __shared__ u16 zl_lds[16 * C];  // 4 KB
    int tid = threadIdx.x;
    int wave = tid >> 6, lane = tid & 63;
    int grp = lane >> 4, l16 = lane & 15;
    int rowbase = blockIdx.x * 16;  // grid is exact: 6250*16 = NN
    const char* gb = (const char*)gin + l16 * 16;

    // -------- issue-early: epilogue operands into registers --------
    float hpre[8];
    float dvr[4];
#pragma unroll
    for (int tt = 0; tt < 2; ++tt) {
        int n = (wave * 2 + tt) * 16 + l16;
#pragma unroll
        for (int r = 0; r < 4; ++r) {
            int m = rowbase + grp * 4 + r;
            hpre[tt * 4 + r] = h32[(size_t)m * C + n];
        }
    }
#pragma unroll
    for (int r = 0; r < 4; ++r) dvr[r] = dinv[rowbase + grp * 4 + r];
    __builtin_amdgcn_sched_barrier(0);  // pin: loads issue before the agg loop

#define ACC8(vv)                                                          \
    {                                                                     \
        u32 x_;                                                           \
        x_ = (u32)(vv).x; a0 += bf2f((u16)x_); a1 += bf2f((u16)(x_ >> 16)); \
        x_ = (u32)(vv).y; a2 += bf2f((u16)x_); a3 += bf2f((u16)(x_ >> 16)); \
        x_ = (u32)(vv).z; a4 += bf2f((u16)x_); a5 += bf2f((u16)(x_ >> 16)); \
        x_ = (u32)(vv).w; a6 += bf2f((u16)x_); a7 += bf2f((u16)(x_ >> 16)); \
    }

    // ---------------- agg phase: 4 nodes per wave ----------------
    for (int it = 0; it < 4; ++it) {
        int lrow = wave * 4 + it;
        int node = rowbase + lrow;
        int deg = __builtin_amdgcn_readfirstlane(cnt[node]);
        const int* cp = csr + (size_t)node * PSTRIDE;
        float a0 = 0.f, a1 = 0.f, a2 = 0.f, a3 = 0.f, a4 = 0.f, a5 = 0.f, a6 = 0.f, a7 = 0.f;
        int nch = (deg + 15) >> 4;  // chunks of 16 neighbors
        if (nch > 0) {
            int dm1 = deg - 1;
            int s0 = cp[min(grp, dm1)];
            int s1 = cp[min(grp + 4, dm1)];
            int s2 = cp[min(grp + 8, dm1)];
            int s3 = cp[min(grp + 12, dm1)];
            for (int c = 0; c < nch; ++c) {
                int4 v0 = *(const int4*)(gb + (size_t)(u32)s0 * 256);
                int4 v1 = *(const int4*)(gb + (size_t)(u32)s1 * 256);
                int4 v2 = *(const int4*)(gb + (size_t)(u32)s2 * 256);
                int4 v3 = *(const int4*)(gb + (size_t)(u32)s3 * 256);
                bool more = (c + 1) < nch;
                if (more) {
                    int nb = (c + 1) << 4;
                    s0 = cp[min(nb + grp, dm1)];
                    s1 = cp[min(nb + grp + 4, dm1)];
                    s2 = cp[min(nb + grp + 8, dm1)];
                    s3 = cp[min(nb + grp + 12, dm1)];
                }
                int cb = c << 4;
                if (cb + 16 <= deg) {  // wave-uniform: full chunk
                    ACC8(v0); ACC8(v1); ACC8(v2); ACC8(v3);
                } else {  // tail: zero-mask invalid rows (adding +0.0 is safe)
                    int m0 = (cb + grp < deg) ? -1 : 0;
                    int m1 = (cb + grp + 4 < deg) ? -1 : 0;
                    int m2 = (cb + grp + 8 < deg) ? -1 : 0;
                    int m3 = (cb + grp + 12 < deg) ? -1 : 0;
                    v0.x &= m0; v0.y &= m0; v0.z &= m0; v0.w &= m0;
                    v1.x &= m1; v1.y &= m1; v1.z &= m1; v1.w &= m1;
                    v2.x &= m2; v2.y &= m2; v2.z &= m2; v2.w &= m2;
                    v3.x &= m3; v3.y &= m3; v3.z &= m3; v3.w &= m3;
                    ACC8(v0); ACC8(v1); ACC8(v2); ACC8(v3);
                }
            }
        }
        a0 += __shfl_xor(a0, 16); a0 += __shfl_xor(a0, 32);
        a1 += __shfl_xor(a1, 16); a1 += __shfl_xor(a1, 32);
        a2 += __shfl_xor(a2, 16); a2 += __shfl_xor(a2, 32);
        a3 += __shfl_xor(a3, 16); a3 += __shfl_xor(a3, 32);
        a4 += __shfl_xor(a4, 16); a4 += __shfl_xor(a4, 32);
        a5 += __shfl_xor(a5, 16); a5 += __shfl_xor(a5, 32);
        a6 += __shfl_xor(a6, 16); a6 += __shfl_xor(a6, 32);
        a7 += __shfl_xor(a7, 16); a7 += __shfl_xor(a7, 32);
        // self-loop term (added once per lane, post-reduce)
        int4 sv = *(const int4*)((const char*)gin + (size_t)node * 256 + l16 * 16);
        ACC8(sv);
        float dv = dinv[node];
        int4 xv = *(const int4*)((const char*)x0bf + (size_t)node * 256 + l16 * 16);
        float av[8] = {a0, a1, a2, a3, a4, a5, a6, a7};
        u32 xs[4] = {(u32)xv.x, (u32)xv.y, (u32)xv.z, (u32)xv.w};
        float xf[8];
        xf[0] = bf2f((u16)xs[0]); xf[1] = bf2f((u16)(xs[0] >> 16));
        xf[2] = bf2f((u16)xs[1]); xf[3] = bf2f((u16)(xs[1] >> 16));
        xf[4] = bf2f((u16)xs[2]); xf[5] = bf2f((u16)(xs[2] >> 16));
        xf[6] = bf2f((u16)xs[3]); xf[7] = bf2f((u16)(xs[3] >> 16));
        u32 hp[4], lp[4];
#pragma unroll
        for (int k = 0; k < 4; ++k) {
            float z0 = 0.9f * dv * av[2 * k] + 0.1f * xf[2 * k];
            float z1 = 0.9f * dv * av[2 * k + 1] + 0.1f * xf[2 * k + 1];
            u16 h0 = f2bf(z0), h1 = f2bf(z1);
            u16 l0 = f2bf(z0 - bf2f(h0)), l1 = f2bf(z1 - bf2f(h1));
            hp[k] = (u32)h0 | ((u32)h1 << 16);
            lp[k] = (u32)l0 | ((u32)l1 << 16);
        }
        int bo = (l16 * 16) ^ ((lrow & 7) << 4);  // swizzled byte off in row
        if (grp == 0) {
            int4 o; o.x = (int)hp[0]; o.y = (int)hp[1]; o.z = (int)hp[2]; o.w = (int)hp[3];
            *(int4*)((char*)zh_lds + lrow * 256 + bo) = o;
        } else if (grp == 1) {
            int4 o; o.x = (int)lp[0]; o.y = (int)lp[1]; o.z = (int)lp[2]; o.w = (int)lp[3];
            *(int4*)((char*)zl_lds + lrow * 256 + bo) = o;
        }
    }
#undef ACC8
    __syncthreads();

    // ---------------- GEMM phase: M=16, wave owns n-tiles t=wave*2,wave*2+1 --
    s16x8 ahi[4], alo[4];
#pragma unroll
    for (int c2 = 0; c2 < 4; ++c2) {
        int bo = (c2 * 64 + grp * 16) ^ ((l16 & 7) << 4);
        ahi[c2] = *(const s16x8*)((const char*)zh_lds + l16 * 256 + bo);
        alo[c2] = *(const s16x8*)((const char*)zl_lds + l16 * 256 + bo);
    }
    f32x4 acc[2];
    acc[0] = f32x4{0.f, 0.f, 0.f, 0.f};
    acc[1] = f32x4{0.f, 0.f, 0.f, 0.f};
#pragma unroll
    for (int c2 = 0; c2 < 4; ++c2) {
#pragma unroll
        for (int tt = 0; tt < 2; ++tt) {
            int t = wave * 2 + tt;
            int widx = (t * 16 + l16) * C + c2 * 32 + grp * 8;
            s16x8 bh = *(const s16x8*)(Wbh + widx);
            s16x8 bl = *(const s16x8*)(Wbl + widx);
            acc[tt] = __builtin_amdgcn_mfma_f32_16x16x32_bf16(ahi[c2], bh, acc[tt], 0, 0, 0);
            acc[tt] = __builtin_amdgcn_mfma_f32_16x16x32_bf16(alo[c2], bh, acc[tt], 0, 0, 0);
            acc[tt] = __builtin_amdgcn_mfma_f32_16x16x32_bf16(ahi[c2], bl, acc[tt], 0, 0, 0);
        }
    }
#pragma unroll
    for (int tt = 0; tt < 2; ++tt) {
        int n = (wave * 2 + tt) * 16 + l16;
#pragma unroll
        for (int r = 0; r < 4; ++r) {
            int m = rowbase + grp * 4 + r;
            size_t idx = (size_t)m * C + n;
            float hn = acc[tt][r] + hpre[tt * 4 + r];
            if (relu) hn = fmaxf(hn, 0.f);
            out32[idx] = hn;
            gout[idx] = f2bf(dvr[r] * hn);
        }
    }
}

// ---------------- host ----------------

extern "C" void kernel_launch(void* const* d_in, const int* in_sizes, int n_in,
                              void* d_out, int out_size, void* d_ws, size_t ws_size,
                              hipStream_t stream) {
    const float* x = (const float*)d_in[0];
    const int* ei = (const int*)d_in[1];
    const float* Wp = (const float*)d_in[2];
    const float* bp = (const float*)d_in[3];
    const float* cw = (const float*)d_in[4];
    const int* row = ei;
    const int* col = ei + NE;

    char* ws = (char*)d_ws;
    size_t o = 0;
    auto alloc = [&](size_t bytes) {
        void* p = ws + o;
        o += (bytes + 255) & ~(size_t)255;
        return p;
    };
    int* cnt = (int*)alloc(NN * 4);
    float* dinv = (float*)alloc(NN * 4);
    int* csr = (int*)alloc((size_t)NN * PSTRIDE * 4);
    u16* x0bf = (u16*)alloc((size_t)NN * C * 2);
    u16* gbufA = (u16*)alloc((size_t)NN * C * 2);
    u16* gbufB = (u16*)alloc((size_t)NN * C * 2);
    float* h32 = (float*)alloc((size_t)NN * C * 4);
    u16* Wbh = (u16*)alloc((size_t)9 * C * C * 2);
    u16* Wbl = (u16*)alloc((size_t)9 * C * C * 2);

    // binning scratch ALIASES x0bf..h32 (76.8+ MB): barr 58.7 MB + bcnt 1.2 MB,
    // fully consumed by fillpass before gemm_proj first writes x0bf/gbufA/h32.
    char* scratch = (char*)x0bf;
    u32* barr = (u32*)scratch;
    u32* bcnt = (u32*)(scratch + (size_t)NBLK * NBUCK * SEGCAP * 4);

    binpass<<<NBLK, 256, 0, stream>>>(row, col, barr, bcnt);
    fillpass<<<NBUCK, 1024, 0, stream>>>(barr, bcnt, csr, cnt, dinv);
    prep_w<<<(9 * C * C + 255) / 256, 256, 0, stream>>>(Wp, cw, Wbh, Wbl);
    gemm_proj<<<(NN + 63) / 64, 256, 0, stream>>>(x, Wbh, Wbl, bp, dinv, x0bf, h32, gbufA);

    u16* ga = gbufA;   // gather-table in
    u16* gb2 = gbufB;  // gather-table out (ping-pong: same-launch R/W otherwise)
    for (int l = 0; l < NLAYERS; ++l) {
        float* out32 = (l == NLAYERS - 1) ? (float*)d_out : h32;
        agg_gemm2<<<NN / 16, 256, 0, stream>>>(
            ga, x0bf, cnt, csr, dinv,
            Wbh + (size_t)(l + 1) * C * C, Wbl + (size_t)(l + 1) * C * C,
            h32, out32, gb2, (l < NLAYERS - 1) ? 1 : 0);
        u16* tmp = ga; ga = gb2; gb2 = tmp;
    }
}